// Round 8
// baseline (104.377 us; speedup 1.0000x reference)
//
#include <hip/hip_runtime.h>
#include <stdint.h>

// ---------------------------------------------------------------------------
// R8: neg restructured to 256-thread blocks; thread (p,j) owns all 4 streams
// (n in {2p,2p+1}) x (h in {0,1}) of column j -- they share kappa[b][j], so a
// SINGLE rejection-candidate stream supplies all 4 w draws (accepted draws of
// one rejection stream are iid target samples -> distribution-exact).
// Directions still collapsed to sufficient statistics (R4), counter-hash RNG
// (R5), msq = 1-mu0^2 (R7). s_ref/s_pos remain threefry-bit-exact (R5 kernel).
// ---------------------------------------------------------------------------

#define NB 4096
#define NNEG 128
#define DD 64
#define NS 8
#define NIT 64

#define LOG2E 1.4426950408889634f
#define LN2   0.6931471805599453f

__device__ __forceinline__ void tf2x32(uint32_t k0, uint32_t k1,
                                       uint32_t x0, uint32_t x1,
                                       uint32_t& y0, uint32_t& y1) {
  uint32_t ks2 = k0 ^ k1 ^ 0x1BD11BDAu;
  x0 += k0; x1 += k1;
#define TFR(r) { x0 += x1; x1 = __builtin_rotateleft32(x1, r); x1 ^= x0; }
  TFR(13) TFR(15) TFR(26) TFR(6)
  x0 += k1; x1 += ks2 + 1u;
  TFR(17) TFR(29) TFR(16) TFR(24)
  x0 += ks2; x1 += k0 + 2u;
  TFR(13) TFR(15) TFR(26) TFR(6)
  x0 += k0; x1 += k1 + 3u;
  TFR(17) TFR(29) TFR(16) TFR(24)
  x0 += k1; x1 += ks2 + 4u;
  TFR(13) TFR(15) TFR(26) TFR(6)
  x0 += ks2; x1 += k0 + 5u;
#undef TFR
  y0 = x0; y1 = x1;
}

__device__ __forceinline__ float u01f(uint32_t bits) {
  return __uint_as_float(0x3F800000u | (bits >> 9)) - 1.0f;
}

// sqrt(2) * erfinv(2*u01 - 0.99999994), Giles poly pre-scaled by sqrt(2).
__device__ __forceinline__ float normal_from_bits(uint32_t bits) {
  float f = u01f(bits);
  float x = fmaf(f, 2.0f, -0.99999994f);
  float s = fmaf(-x, x, 1.0f);
  float w2 = __builtin_amdgcn_logf(s);
  float p;
  if (w2 > -7.2134752f) {
    float y = fmaf(w2, -0.69314718f, -2.5f);
    p =              3.9742602e-08f;
    p = fmaf(p, y,   4.8546266e-07f);
    p = fmaf(p, y,  -4.9828227e-06f);
    p = fmaf(p, y,  -6.2105281e-06f);
    p = fmaf(p, y,   3.0912003e-04f);
    p = fmaf(p, y,  -1.7730349e-03f);
    p = fmaf(p, y,  -5.9081340e-03f);
    p = fmaf(p, y,   0.34880266f);
    p = fmaf(p, y,   2.1233135f);
  } else {
    float y = __builtin_amdgcn_sqrtf(-0.69314718f * w2) - 3.0f;
    p =             -2.8314572e-04f;
    p = fmaf(p, y,   1.4276565e-04f);
    p = fmaf(p, y,   1.9082601e-03f);
    p = fmaf(p, y,  -5.1950123e-03f);
    p = fmaf(p, y,   8.1168897e-03f);
    p = fmaf(p, y,  -1.0779792e-02f);
    p = fmaf(p, y,   1.3348578e-02f);
    p = fmaf(p, y,   1.4165811f);
    p = fmaf(p, y,   4.0064333f);
  }
  return p * x;
}

__device__ __forceinline__ float wave_max(float v) {
  for (int m = 32; m; m >>= 1) v = fmaxf(v, __shfl_xor(v, m, 64));
  return v;
}
__device__ __forceinline__ float wave_sum(float v) {
  for (int m = 32; m; m >>= 1) v += __shfl_xor(v, m, 64);
  return v;
}

// --- cheap counter-hash RNG ------------------------------------------------
__device__ __forceinline__ uint32_t hash32(uint32_t x) {
  x *= 0x9E3779B9u;
  x ^= x >> 16; x *= 0x21f0aaadu;
  x ^= x >> 15; x *= 0x735a2d97u;
  x ^= x >> 15;
  return x;
}

__device__ __forceinline__ float2 bm_pair(uint32_t bits) {
  float u1 = (float)((bits & 0xffffu) + 1u) * (1.0f / 65536.0f);
  float u2 = (float)(bits >> 16) * (1.0f / 65536.0f);
  float r  = __builtin_amdgcn_sqrtf(-2.0f * LN2 * __builtin_amdgcn_logf(u1));
  return {r * __builtin_amdgcn_cosf(u2), r * __builtin_amdgcn_sinf(u2)};
}
__device__ __forceinline__ float bm_one(uint32_t bits) {
  float u1 = (float)((bits & 0xffffu) + 1u) * (1.0f / 65536.0f);
  float u2 = (float)(bits >> 16) * (1.0f / 65536.0f);
  float r  = __builtin_amdgcn_sqrtf(-2.0f * LN2 * __builtin_amdgcn_logf(u1));
  return r * __builtin_amdgcn_cosf(u2);
}

// Exact chi^2_61 via Marsaglia-Tsang Gamma(30.5).
__device__ __forceinline__ float chi2_61(uint32_t cnt) {
  const float dM = 30.166666667f, cM = 0.060689937f;
  float vAcc = 1.0f;
  bool done = false;
  for (int g = 0; g < 6; ++g) {
    float x = bm_one(hash32(cnt + 2u * g));
    float u = u01f(hash32(cnt + 2u * g + 1u));
    float t = fmaf(cM, x, 1.0f);
    float v = t * t * t;
    float rhs = fmaf(0.5f, x * x,
                     dM * (1.0f - v) + dM * LN2 * __builtin_amdgcn_logf(v));
    float lnu = LN2 * __builtin_amdgcn_logf(u);
    if (!done && (lnu < rhs)) { vAcc = v; done = true; }
    if (__all(done)) break;
  }
  return 60.333333333f * vAcc;
}

// ---------------------------------------------------------------------------
// Kernel 1: s_ref / s_pos, bit-exact, one WAVE per (g, r) row-pair.
// ---------------------------------------------------------------------------
__global__ __launch_bounds__(512) void refpos_wave(
    const float* __restrict__ mu_ref, const float* __restrict__ kap_ref,
    const float* __restrict__ mu_pos, const float* __restrict__ kap_pos,
    float* __restrict__ s_ref, float* __restrict__ s_pos) {
  __shared__ uint4 ktS[2][64];   // per-iteration keys {eps0,eps1,u0,u1}
  __shared__ uint2 kvS[2];       // v-keys per group
  int t = threadIdx.x;

  if (t < 128) {
    int g = t >> 6, it = t & 63;
    uint32_t gk0, gk1;
    if (g == 0) {
      uint32_t A0, B0, A1, B1;
      tf2x32(0u, 42u, 0u, 3u, A0, B0);
      tf2x32(0u, 42u, 1u, 4u, A1, B1);
      gk0 = A0; gk1 = A1;                       // kr
    } else {
      uint32_t A2, B2, A0, B0;
      tf2x32(0u, 42u, 2u, 5u, A2, B2);
      tf2x32(0u, 42u, 0u, 3u, A0, B0);
      gk0 = A2; gk1 = B0;                       // kp
    }
    uint32_t C0, D0, C1, D1;
    tf2x32(gk0, gk1, 0u, 2u, C0, D0);
    tf2x32(gk0, gk1, 1u, 3u, C1, D1);
    uint32_t E0, E1;
    tf2x32(C0, C1, 0u, (uint32_t)it, E0, E1);
    uint32_t F0, G0, F1, G1;
    tf2x32(E0, E1, 0u, 2u, F0, G0);
    tf2x32(E0, E1, 1u, 3u, F1, G1);
    ktS[g][it] = {F0, F1, G0, G1};
    if (it == 0) kvS[g] = {D0, D1};
  }
  __syncthreads();

  int wave_id = blockIdx.x * 8 + (t >> 6);      // 0..32767
  int lane = t & 63;
  int g = wave_id >> 14;                        // 0=ref, 1=pos
  int r = wave_id & 16383;                      // n*4096 + b
  int b = r & 4095;
  const float* mu = (g == 0 ? mu_ref : mu_pos) + (size_t)b * DD;
  float kap = (g == 0 ? kap_ref[b] : kap_pos[b]);

  // ---- w phase: lane i evaluates rejection iteration i for both halves ----
  float s   = __builtin_amdgcn_sqrtf(fmaf(4.0f * kap, kap, 3969.0f));
  float bbv = (s - 2.0f * kap) * (1.0f / 63.0f);
  float aav = (63.0f + 2.0f * kap + s) * 0.25f;
  float ab2 = 2.0f * aav * bbv;
  float dcv = 2.0f * ab2 * __builtin_amdgcn_rcpf(1.0f + bbv) - 261.01749f;
  const float K = 43.668274f;
  float C   = fmaf(K, __builtin_amdgcn_logf(ab2), dcv);
  float om_b = 1.0f - bbv, op_b = 1.0f + bbv;

  uint4 kk = ktS[g][lane];
  uint32_t e0, e1, g0, g1;
  tf2x32(kk.x, kk.y, (uint32_t)r, (uint32_t)r + 16384u, e0, e1);
  tf2x32(kk.z, kk.w, (uint32_t)r, (uint32_t)r + 16384u, g0, g1);
  float ct0, ct1;
  bool acc0, acc1;
  {
    float eps = fminf(fmaxf(u01f(e0), 1e-7f), 0.99999988f);
    float den = fmaf(-om_b, eps, 1.0f);
    float id  = __builtin_amdgcn_rcpf(den);
    ct0 = fmaf(-op_b, eps, 1.0f) * id;
    float tv  = ab2 * id;
    float lhs = fmaf(-K, __builtin_amdgcn_logf(den), C) - tv;
    acc0 = lhs >= LN2 * __builtin_amdgcn_logf(u01f(g0));
  }
  {
    float eps = fminf(fmaxf(u01f(e1), 1e-7f), 0.99999988f);
    float den = fmaf(-om_b, eps, 1.0f);
    float id  = __builtin_amdgcn_rcpf(den);
    ct1 = fmaf(-op_b, eps, 1.0f) * id;
    float tv  = ab2 * id;
    float lhs = fmaf(-K, __builtin_amdgcn_logf(den), C) - tv;
    acc1 = lhs >= LN2 * __builtin_amdgcn_logf(u01f(g1));
  }
  unsigned long long m0 = __ballot(acc0);
  unsigned long long m1 = __ballot(acc1);
  int f0i = __ffsll((long long)m0);
  int f1i = __ffsll((long long)m1);
  float w0 = f0i ? __shfl(ct0, f0i - 1, 64) : 1.0f;
  float w1 = f1i ? __shfl(ct1, f1i - 1, 64) : 1.0f;

  // ---- v phase: lane d handles dimension d ----
  uint2 kv = kvS[g];
  float v0 = 0.f, v1 = 0.f, m1v = 0.f;
  if (lane < 63) {
    uint32_t Lv = (uint32_t)r * 63u + (uint32_t)lane;
    uint32_t y0, y1;
    tf2x32(kv.x, kv.y, Lv, Lv + 1032192u, y0, y1);
    v0 = normal_from_bits(y0);
    v1 = normal_from_bits(y1);
    m1v = mu[lane + 1];
  }
  float mu0 = mu[0];
  float ss0 = wave_sum(v0 * v0);
  float ss1 = wave_sum(v1 * v1);
  float mv0 = wave_sum(m1v * v0);
  float mv1 = wave_sum(m1v * v1);
  float msq = wave_sum(m1v * m1v);

  float c0 = __builtin_amdgcn_sqrtf(fmaxf(1.0f - w0 * w0, 1e-7f));
  float c1 = __builtin_amdgcn_sqrtf(fmaxf(1.0f - w1 * w1, 1e-7f));
  float e0m = 1.0f - mu0;
  float nu  = fmaxf(__builtin_amdgcn_sqrtf(e0m * e0m + msq), 1e-7f);
  float inu = __builtin_amdgcn_rcpf(nu);
  float f0 = c0 * __builtin_amdgcn_rsqf(ss0);
  float f1 = c1 * __builtin_amdgcn_rsqf(ss1);
  float dot0 = (w0 * e0m - f0 * mv0) * inu;
  float dot1 = (w1 * e0m - f1 * mv1) * inu;

  float* outp = (g == 0 ? s_ref : s_pos);
  float* row0 = outp + (size_t)r * DD;
  float* row1 = outp + (size_t)(r + 16384) * DD;
  if (lane < 63) {
    float uh = -m1v * inu;
    row0[lane + 1] = f0 * v0 - 2.0f * dot0 * uh;
    row1[lane + 1] = f1 * v1 - 2.0f * dot1 * uh;
  } else {
    row0[0] = w0 - 2.0f * dot0 * (e0m * inu);
    row1[0] = w1 - 2.0f * dot1 * (e0m * inu);
  }
}

// ---------------------------------------------------------------------------
// Kernel 2: negatives. Block = b, 256 threads = (p in 0..1) x (j in 0..127).
// Thread owns 4 streams (n in {2p,2p+1}) x (h in {0,1}), all sharing
// kappa[b][j]: ONE rejection-candidate stream yields the 4 w draws.
// ---------------------------------------------------------------------------
__global__ __launch_bounds__(256, 4) void neg_kernel(
    const float* __restrict__ mu_neg, const float* __restrict__ kap_neg,
    const float* __restrict__ s_ref, const float* __restrict__ s_pos,
    const float* __restrict__ loss_kappa, float* __restrict__ t_out) {
  __shared__ float muS[128 * 65];   // stride-65: conflict-free scalar reads
  __shared__ float2 rS[4][64];      // [n][d] = (h0, h1)
  __shared__ float posS[8][64];     // [h*4+n][d]
  __shared__ float rrS[8];          // [h*4+n] = sum_{d>=1} r[d]^2
  __shared__ float lseS[8];         // [h*4+n]
  __shared__ float wredS[4][4];     // [wave][ (nl<<1)|h ] partial exp-sums
  int b = blockIdx.x;
  int t = threadIdx.x;
  int wid = t >> 6;                 // 0..3
  int lane = t & 63;
  int p = t >> 7;                   // 0..1
  int j = t & 127;

  // stage mu (float4 global loads, scalar writes into stride-65 rows)
  const float4* mublk4 = (const float4*)(mu_neg + (size_t)b * (NNEG * DD));
#pragma unroll
  for (int i = t; i < NNEG * 16; i += 256) {
    float4 v4 = mublk4[i];
    float* dst = &muS[(i >> 4) * 65 + ((i & 15) << 2)];
    dst[0] = v4.x; dst[1] = v4.y; dst[2] = v4.z; dst[3] = v4.w;
  }
  {
    int nn = wid;
    size_t r0 = (size_t)(nn * 4096 + b) * DD;
    size_t r1 = (size_t)(nn * 4096 + b + 16384) * DD;
    float rv0 = s_ref[r0 + lane], rv1 = s_ref[r1 + lane];
    rS[nn][lane] = {rv0, rv1};
    posS[nn][lane]     = s_pos[r0 + lane];
    posS[4 + nn][lane] = s_pos[r1 + lane];
    float q0 = wave_sum(lane > 0 ? rv0 * rv0 : 0.0f);
    float q1 = wave_sum(lane > 0 ? rv1 * rv1 : 0.0f);
    if (lane == 0) { rrS[nn] = q0; rrS[4 + nn] = q1; }
  }
  __syncthreads();

  // ---- w phase: one shared candidate stream -> 4 accepts ----
  float kap = kap_neg[(size_t)b * NNEG + j];
  float s   = __builtin_amdgcn_sqrtf(fmaf(4.0f * kap, kap, 3969.0f));
  float bb  = (s - 2.0f * kap) * (1.0f / 63.0f);
  float aa  = (63.0f + 2.0f * kap + s) * 0.25f;
  float ab2 = 2.0f * aa * bb;
  float dc  = 2.0f * ab2 * __builtin_amdgcn_rcpf(1.0f + bb) - 261.01749f;
  const float K = 43.668274f;
  float C   = fmaf(K, __builtin_amdgcn_logf(ab2), dc);
  float om_b = 1.0f - bb, op_b = 1.0f + bb;
  uint32_t wb = 0x40000000u + (((uint32_t)b * 128u + (uint32_t)j) << 7)
                            + ((uint32_t)p << 6);
  float w00 = 1.f, w01 = 1.f, w10 = 1.f, w11 = 1.f;
  int k = 0;
  for (int it = 0; it < 63; ++it) {
    if (__all(k >= 4)) break;
    uint32_t bits = hash32(wb + (uint32_t)it);
    float eps = fmaxf((float)(bits & 0xffffu) * (1.0f / 65536.0f), 1e-7f);
    float uu  = (float)((bits >> 16) + 1u) * (1.0f / 65536.0f);
    float den = fmaf(-om_b, eps, 1.0f);
    float id  = __builtin_amdgcn_rcpf(den);
    float ct  = fmaf(-op_b, eps, 1.0f) * id;
    float tv  = ab2 * id;
    float lhs = fmaf(-K, __builtin_amdgcn_logf(den), C) - tv;
    float rhs = LN2 * __builtin_amdgcn_logf(uu);
    bool acc = (lhs >= rhs) && (k < 4);
    if (acc) {
      if (k == 0)      w00 = ct;
      else if (k == 1) w01 = ct;
      else if (k == 2) w10 = ct;
      else             w11 = ct;
      ++k;
    }
  }

  // ---- dot phase: mu-row once, 4 dots ----
  const float* myMu = &muS[j * 65];
  const float2* r0p = rS[2 * p];
  const float2* r1p = rS[2 * p + 1];
  float mu0 = myMu[0];
  float rm00 = 0.f, rm01 = 0.f, rm10 = 0.f, rm11 = 0.f;
#pragma unroll 7
  for (int d = 0; d < DD - 1; ++d) {
    float m1 = myMu[d + 1];
    float2 rA = r0p[d + 1];
    float2 rB = r1p[d + 1];
    rm00 = fmaf(rA.x, m1, rm00);
    rm01 = fmaf(rA.y, m1, rm01);
    rm10 = fmaf(rB.x, m1, rm10);
    rm11 = fmaf(rB.y, m1, rm11);
  }
  float msq = fmaxf(fmaf(-mu0, mu0, 1.0f), 0.0f);   // unit rows
  float lk  = loss_kappa[0];
  float e0m = 1.0f - mu0;
  float nu  = fmaxf(__builtin_amdgcn_sqrtf(e0m + e0m), 1e-7f);
  float inu = __builtin_amdgcn_rcpf(nu);
  float2 rf0 = r0p[0];
  float2 rf1 = r1p[0];

  // ---- 4 sim blocks (independent -> ILP) ----
  int n0 = 2 * p, n1 = 2 * p + 1;
  auto simf = [&](float wv, float rm, float rfv, float rr, uint32_t Lh) {
    uint32_t cnt = Lh << 4;
    float2 ab = bm_pair(hash32(cnt + 15u));
    float s61 = chi2_61(cnt);
    float ss  = fmaf(ab.x, ab.x, fmaf(ab.y, ab.y, s61));
    float nr  = fmaxf(__builtin_amdgcn_sqrtf(rr), 1e-6f);
    float pp  = rm * __builtin_amdgcn_rcpf(nr);
    float qq  = __builtin_amdgcn_sqrtf(fmaxf(msq - pp * pp, 0.0f));
    float rv  = nr * ab.x;
    float mv  = fmaf(pp, ab.x, qq * ab.y);
    float c   = __builtin_amdgcn_sqrtf(fmaxf(1.0f - wv * wv, 1e-7f));
    float f   = c * __builtin_amdgcn_rsqf(ss);
    float dd  = (wv * e0m - f * mv) * inu;
    float rz  = rfv * wv + f * rv;
    float ru  = (rfv * e0m - rm) * inu;
    return lk * (rz - 2.0f * dd * ru);
  };
  uint32_t L0 = (uint32_t)(n0 * 4096 + b) * 128u + (uint32_t)j;
  uint32_t L1 = (uint32_t)(n1 * 4096 + b) * 128u + (uint32_t)j;
  float s00 = simf(w00, rm00, rf0.x, rrS[n0],     L0);
  float s01 = simf(w01, rm01, rf0.y, rrS[4 + n0], L0 + 2097152u);
  float s10 = simf(w10, rm10, rf1.x, rrS[n1],     L1);
  float s11 = simf(w11, rm11, rf1.y, rrS[4 + n1], L1 + 2097152u);

  // ---- lse over j (no-max: |sim|*LOG2E < ~70, safe in f32) ----
  float e00 = __builtin_amdgcn_exp2f(s00 * LOG2E);
  float e01 = __builtin_amdgcn_exp2f(s01 * LOG2E);
  float e10 = __builtin_amdgcn_exp2f(s10 * LOG2E);
  float e11 = __builtin_amdgcn_exp2f(s11 * LOG2E);
  float z00 = wave_sum(e00);
  float z01 = wave_sum(e01);
  float z10 = wave_sum(e10);
  float z11 = wave_sum(e11);
  if (lane == 0) {
    wredS[wid][0] = z00; wredS[wid][1] = z01;
    wredS[wid][2] = z10; wredS[wid][3] = z11;
  }
  __syncthreads();
  if (t < 8) {
    int h = t >> 2, n = t & 3;
    int wbase = (n >> 1) * 2;                  // waves {0,1} for n<2, {2,3} else
    int c = ((n & 1) << 1) | h;
    float sm = wredS[wbase][c] + wredS[wbase + 1][c];
    lseS[h * 4 + n] = LN2 * __builtin_amdgcn_logf(sm);
  }
  __syncthreads();

  // ---- sp dot + t_out: wave wid handles n = wid, both h ----
  {
    int n = wid;
    float2 rv = rS[n][lane];
    float sp0 = wave_sum(rv.x * posS[n][lane]) * lk;
    float sp1 = wave_sum(rv.y * posS[4 + n][lane]) * lk;
    if (lane == 0) {
      float lse0 = lseS[n], lse1 = lseS[4 + n];
      float m0  = fmaxf(sp0, lse0);
      float ld0 = m0 + LN2 * __builtin_amdgcn_logf(
          __builtin_amdgcn_exp2f((sp0 - m0) * LOG2E) +
          __builtin_amdgcn_exp2f((lse0 - m0) * LOG2E));
      t_out[n * 4096 + b] = sp0 - ld0;
      float m1  = fmaxf(sp1, lse1);
      float ld1 = m1 + LN2 * __builtin_amdgcn_logf(
          __builtin_amdgcn_exp2f((sp1 - m1) * LOG2E) +
          __builtin_amdgcn_exp2f((lse1 - m1) * LOG2E));
      t_out[n * 4096 + b + 16384] = sp1 - ld1;
    }
  }
}

// ---------------------------------------------------------------------------
// Kernel 3: log_prob per b = logsumexp_n(t) - log(8); out = -mean_b.
// ---------------------------------------------------------------------------
__global__ __launch_bounds__(256) void final_kernel(
    const float* __restrict__ t_tab, float* __restrict__ out) {
  __shared__ float red[256];
  int t = threadIdx.x;
  float acc = 0.f;
  for (int b = t; b < NB; b += 256) {
    float mx = -INFINITY;
    for (int n = 0; n < NS; ++n) mx = fmaxf(mx, t_tab[n * NB + b]);
    float s = 0.f;
    for (int n = 0; n < NS; ++n)
      s += __builtin_amdgcn_exp2f((t_tab[n * NB + b] - mx) * LOG2E);
    acc += mx + LN2 * __builtin_amdgcn_logf(s) - 2.0794415f; // log(8)
  }
  red[t] = acc; __syncthreads();
  for (int s = 128; s > 0; s >>= 1) {
    if (t < s) red[t] += red[t + s];
    __syncthreads();
  }
  if (t == 0) out[0] = -(red[0] / (float)NB);
}

extern "C" void kernel_launch(void* const* d_in, const int* in_sizes, int n_in,
                              void* d_out, int out_size, void* d_ws, size_t ws_size,
                              hipStream_t stream) {
  const float* mu_ref  = (const float*)d_in[0];
  const float* kap_ref = (const float*)d_in[1];
  const float* mu_pos  = (const float*)d_in[2];
  const float* kap_pos = (const float*)d_in[3];
  const float* mu_neg  = (const float*)d_in[4];
  const float* kap_neg = (const float*)d_in[5];
  const float* lk      = (const float*)d_in[6];
  float* out = (float*)d_out;

  uint8_t* ws = (uint8_t*)d_ws;
  float* s_ref = (float*)ws;                                // 8 MB
  float* s_pos = (float*)(ws + 8388608);                    // 8 MB
  float* t_tab = (float*)(ws + 2 * 8388608);                // 128 KB

  refpos_wave<<<4096, 512, 0, stream>>>(mu_ref, kap_ref, mu_pos, kap_pos,
                                        s_ref, s_pos);
  neg_kernel<<<NB, 256, 0, stream>>>(mu_neg, kap_neg,
                                     s_ref, s_pos, lk, t_tab);
  final_kernel<<<1, 256, 0, stream>>>(t_tab, out);
}

// Round 9
// 95.623 us; speedup vs baseline: 1.0915x; 1.0915x over previous
//
#include <hip/hip_runtime.h>
#include <stdint.h>

// ---------------------------------------------------------------------------
// R9 = R7 structure (512-thread neg blocks, 75% occupancy) + per-thread wins:
//  - shared-candidate w: thread (n,j)'s two h-streams share kappa -> ONE
//    rejection-candidate stream yields both draws (distribution-exact).
//  - Wilson-Hilferty chi^2_61 (cube-of-normal) replaces the MT rejection loop.
//  - no-max logsumexp over j (|sim|<=~48, exp2 args safe in f32).
// s_ref/s_pos remain threefry2x32 bit-exact (wave-parallel kernel).
// ---------------------------------------------------------------------------

#define NB 4096
#define NNEG 128
#define DD 64
#define NS 8
#define NIT 64

#define LOG2E 1.4426950408889634f
#define LN2   0.6931471805599453f

__device__ __forceinline__ void tf2x32(uint32_t k0, uint32_t k1,
                                       uint32_t x0, uint32_t x1,
                                       uint32_t& y0, uint32_t& y1) {
  uint32_t ks2 = k0 ^ k1 ^ 0x1BD11BDAu;
  x0 += k0; x1 += k1;
#define TFR(r) { x0 += x1; x1 = __builtin_rotateleft32(x1, r); x1 ^= x0; }
  TFR(13) TFR(15) TFR(26) TFR(6)
  x0 += k1; x1 += ks2 + 1u;
  TFR(17) TFR(29) TFR(16) TFR(24)
  x0 += ks2; x1 += k0 + 2u;
  TFR(13) TFR(15) TFR(26) TFR(6)
  x0 += k0; x1 += k1 + 3u;
  TFR(17) TFR(29) TFR(16) TFR(24)
  x0 += k1; x1 += ks2 + 4u;
  TFR(13) TFR(15) TFR(26) TFR(6)
  x0 += ks2; x1 += k0 + 5u;
#undef TFR
  y0 = x0; y1 = x1;
}

__device__ __forceinline__ float u01f(uint32_t bits) {
  return __uint_as_float(0x3F800000u | (bits >> 9)) - 1.0f;
}

// sqrt(2) * erfinv(2*u01 - 0.99999994), Giles poly pre-scaled by sqrt(2).
__device__ __forceinline__ float normal_from_bits(uint32_t bits) {
  float f = u01f(bits);
  float x = fmaf(f, 2.0f, -0.99999994f);
  float s = fmaf(-x, x, 1.0f);
  float w2 = __builtin_amdgcn_logf(s);
  float p;
  if (w2 > -7.2134752f) {
    float y = fmaf(w2, -0.69314718f, -2.5f);
    p =              3.9742602e-08f;
    p = fmaf(p, y,   4.8546266e-07f);
    p = fmaf(p, y,  -4.9828227e-06f);
    p = fmaf(p, y,  -6.2105281e-06f);
    p = fmaf(p, y,   3.0912003e-04f);
    p = fmaf(p, y,  -1.7730349e-03f);
    p = fmaf(p, y,  -5.9081340e-03f);
    p = fmaf(p, y,   0.34880266f);
    p = fmaf(p, y,   2.1233135f);
  } else {
    float y = __builtin_amdgcn_sqrtf(-0.69314718f * w2) - 3.0f;
    p =             -2.8314572e-04f;
    p = fmaf(p, y,   1.4276565e-04f);
    p = fmaf(p, y,   1.9082601e-03f);
    p = fmaf(p, y,  -5.1950123e-03f);
    p = fmaf(p, y,   8.1168897e-03f);
    p = fmaf(p, y,  -1.0779792e-02f);
    p = fmaf(p, y,   1.3348578e-02f);
    p = fmaf(p, y,   1.4165811f);
    p = fmaf(p, y,   4.0064333f);
  }
  return p * x;
}

struct WPair { float lo, hi; };

__device__ __forceinline__ float wave_sum(float v) {
  for (int m = 32; m; m >>= 1) v += __shfl_xor(v, m, 64);
  return v;
}

// --- cheap counter-hash RNG ------------------------------------------------
__device__ __forceinline__ uint32_t hash32(uint32_t x) {
  x *= 0x9E3779B9u;
  x ^= x >> 16; x *= 0x21f0aaadu;
  x ^= x >> 15; x *= 0x735a2d97u;
  x ^= x >> 15;
  return x;
}

__device__ __forceinline__ float2 bm_pair(uint32_t bits) {
  float u1 = (float)((bits & 0xffffu) + 1u) * (1.0f / 65536.0f);
  float u2 = (float)(bits >> 16) * (1.0f / 65536.0f);
  float r  = __builtin_amdgcn_sqrtf(-2.0f * LN2 * __builtin_amdgcn_logf(u1));
  return {r * __builtin_amdgcn_cosf(u2), r * __builtin_amdgcn_sinf(u2)};
}
__device__ __forceinline__ float bm_one(uint32_t bits) {
  float u1 = (float)((bits & 0xffffu) + 1u) * (1.0f / 65536.0f);
  float u2 = (float)(bits >> 16) * (1.0f / 65536.0f);
  float r  = __builtin_amdgcn_sqrtf(-2.0f * LN2 * __builtin_amdgcn_logf(u1));
  return r * __builtin_amdgcn_cosf(u2);
}

// Shared-candidate w rejection: one stream supplies both h-draws (same kappa).
__device__ WPair w_pair_shared(float kappa, uint32_t L) {
  float s   = __builtin_amdgcn_sqrtf(fmaf(4.0f * kappa, kappa, 3969.0f));
  float bb  = (s - 2.0f * kappa) * (1.0f / 63.0f);
  float aa  = (63.0f + 2.0f * kappa + s) * 0.25f;
  float ab2 = 2.0f * aa * bb;
  float dc  = 2.0f * ab2 * __builtin_amdgcn_rcpf(1.0f + bb) - 261.01749f;
  const float K = 43.668274f;
  float C   = fmaf(K, __builtin_amdgcn_logf(ab2), dc);
  float om_b = 1.0f - bb, op_b = 1.0f + bb;
  uint32_t base = 0x40000000u + (L << 6);
  float w0 = 1.0f, w1 = 1.0f;
  int k = 0;
  for (int it = 0; it < NIT; ++it) {
    if (__all(k >= 2)) break;
    uint32_t bits = hash32(base + (uint32_t)it);
    float eps = fmaxf((float)(bits & 0xffffu) * (1.0f / 65536.0f), 1e-7f);
    float uu  = (float)((bits >> 16) + 1u) * (1.0f / 65536.0f);
    float den = fmaf(-om_b, eps, 1.0f);
    float id  = __builtin_amdgcn_rcpf(den);
    float ct  = fmaf(-op_b, eps, 1.0f) * id;
    float tv  = ab2 * id;
    float lhs = fmaf(-K, __builtin_amdgcn_logf(den), C) - tv;
    bool acc = (lhs >= LN2 * __builtin_amdgcn_logf(uu)) && (k < 2);
    if (acc) {
      if (k == 0) w0 = ct; else w1 = ct;
      ++k;
    }
  }
  return {w0, w1};
}

// ---------------------------------------------------------------------------
// Kernel 1: s_ref / s_pos, bit-exact, one WAVE per (g, r) row-pair.
// ---------------------------------------------------------------------------
__global__ __launch_bounds__(512) void refpos_wave(
    const float* __restrict__ mu_ref, const float* __restrict__ kap_ref,
    const float* __restrict__ mu_pos, const float* __restrict__ kap_pos,
    float* __restrict__ s_ref, float* __restrict__ s_pos) {
  __shared__ uint4 ktS[2][64];   // per-iteration keys {eps0,eps1,u0,u1}
  __shared__ uint2 kvS[2];       // v-keys per group
  int t = threadIdx.x;

  if (t < 128) {
    int g = t >> 6, it = t & 63;
    uint32_t gk0, gk1;
    if (g == 0) {
      uint32_t A0, B0, A1, B1;
      tf2x32(0u, 42u, 0u, 3u, A0, B0);
      tf2x32(0u, 42u, 1u, 4u, A1, B1);
      gk0 = A0; gk1 = A1;                       // kr
    } else {
      uint32_t A2, B2, A0, B0;
      tf2x32(0u, 42u, 2u, 5u, A2, B2);
      tf2x32(0u, 42u, 0u, 3u, A0, B0);
      gk0 = A2; gk1 = B0;                       // kp
    }
    uint32_t C0, D0, C1, D1;
    tf2x32(gk0, gk1, 0u, 2u, C0, D0);
    tf2x32(gk0, gk1, 1u, 3u, C1, D1);
    uint32_t E0, E1;
    tf2x32(C0, C1, 0u, (uint32_t)it, E0, E1);
    uint32_t F0, G0, F1, G1;
    tf2x32(E0, E1, 0u, 2u, F0, G0);
    tf2x32(E0, E1, 1u, 3u, F1, G1);
    ktS[g][it] = {F0, F1, G0, G1};
    if (it == 0) kvS[g] = {D0, D1};
  }
  __syncthreads();

  int wave_id = blockIdx.x * 8 + (t >> 6);      // 0..32767
  int lane = t & 63;
  int g = wave_id >> 14;                        // 0=ref, 1=pos
  int r = wave_id & 16383;                      // n*4096 + b
  int b = r & 4095;
  const float* mu = (g == 0 ? mu_ref : mu_pos) + (size_t)b * DD;
  float kap = (g == 0 ? kap_ref[b] : kap_pos[b]);

  // ---- w phase: lane i evaluates rejection iteration i for both halves ----
  float s   = __builtin_amdgcn_sqrtf(fmaf(4.0f * kap, kap, 3969.0f));
  float bbv = (s - 2.0f * kap) * (1.0f / 63.0f);
  float aav = (63.0f + 2.0f * kap + s) * 0.25f;
  float ab2 = 2.0f * aav * bbv;
  float dcv = 2.0f * ab2 * __builtin_amdgcn_rcpf(1.0f + bbv) - 261.01749f;
  const float K = 43.668274f;
  float C   = fmaf(K, __builtin_amdgcn_logf(ab2), dcv);
  float om_b = 1.0f - bbv, op_b = 1.0f + bbv;

  uint4 kk = ktS[g][lane];
  uint32_t e0, e1, g0, g1;
  tf2x32(kk.x, kk.y, (uint32_t)r, (uint32_t)r + 16384u, e0, e1);
  tf2x32(kk.z, kk.w, (uint32_t)r, (uint32_t)r + 16384u, g0, g1);
  float ct0, ct1;
  bool acc0, acc1;
  {
    float eps = fminf(fmaxf(u01f(e0), 1e-7f), 0.99999988f);
    float den = fmaf(-om_b, eps, 1.0f);
    float id  = __builtin_amdgcn_rcpf(den);
    ct0 = fmaf(-op_b, eps, 1.0f) * id;
    float tv  = ab2 * id;
    float lhs = fmaf(-K, __builtin_amdgcn_logf(den), C) - tv;
    acc0 = lhs >= LN2 * __builtin_amdgcn_logf(u01f(g0));
  }
  {
    float eps = fminf(fmaxf(u01f(e1), 1e-7f), 0.99999988f);
    float den = fmaf(-om_b, eps, 1.0f);
    float id  = __builtin_amdgcn_rcpf(den);
    ct1 = fmaf(-op_b, eps, 1.0f) * id;
    float tv  = ab2 * id;
    float lhs = fmaf(-K, __builtin_amdgcn_logf(den), C) - tv;
    acc1 = lhs >= LN2 * __builtin_amdgcn_logf(u01f(g1));
  }
  unsigned long long m0 = __ballot(acc0);
  unsigned long long m1 = __ballot(acc1);
  int f0i = __ffsll((long long)m0);
  int f1i = __ffsll((long long)m1);
  float w0 = f0i ? __shfl(ct0, f0i - 1, 64) : 1.0f;
  float w1 = f1i ? __shfl(ct1, f1i - 1, 64) : 1.0f;

  // ---- v phase: lane d handles dimension d ----
  uint2 kv = kvS[g];
  float v0 = 0.f, v1 = 0.f, m1v = 0.f;
  if (lane < 63) {
    uint32_t Lv = (uint32_t)r * 63u + (uint32_t)lane;
    uint32_t y0, y1;
    tf2x32(kv.x, kv.y, Lv, Lv + 1032192u, y0, y1);
    v0 = normal_from_bits(y0);
    v1 = normal_from_bits(y1);
    m1v = mu[lane + 1];
  }
  float mu0 = mu[0];
  float ss0 = wave_sum(v0 * v0);
  float ss1 = wave_sum(v1 * v1);
  float mv0 = wave_sum(m1v * v0);
  float mv1 = wave_sum(m1v * v1);
  float msq = wave_sum(m1v * m1v);

  float c0 = __builtin_amdgcn_sqrtf(fmaxf(1.0f - w0 * w0, 1e-7f));
  float c1 = __builtin_amdgcn_sqrtf(fmaxf(1.0f - w1 * w1, 1e-7f));
  float e0m = 1.0f - mu0;
  float nu  = fmaxf(__builtin_amdgcn_sqrtf(e0m * e0m + msq), 1e-7f);
  float inu = __builtin_amdgcn_rcpf(nu);
  float f0 = c0 * __builtin_amdgcn_rsqf(ss0);
  float f1 = c1 * __builtin_amdgcn_rsqf(ss1);
  float dot0 = (w0 * e0m - f0 * mv0) * inu;
  float dot1 = (w1 * e0m - f1 * mv1) * inu;

  float* outp = (g == 0 ? s_ref : s_pos);
  float* row0 = outp + (size_t)r * DD;
  float* row1 = outp + (size_t)(r + 16384) * DD;
  if (lane < 63) {
    float uh = -m1v * inu;
    row0[lane + 1] = f0 * v0 - 2.0f * dot0 * uh;
    row1[lane + 1] = f1 * v1 - 2.0f * dot1 * uh;
  } else {
    row0[0] = w0 - 2.0f * dot0 * (e0m * inu);
    row1[0] = w1 - 2.0f * dot1 * (e0m * inu);
  }
}

// ---------------------------------------------------------------------------
// Kernel 2: negatives. Block = b (512 threads = 4 n-groups x 128 j), R7 shape.
// Shared-candidate w, WH chi^2_61, no-max lse.
// ---------------------------------------------------------------------------
__global__ __launch_bounds__(512, 4) void neg_kernel(
    const float* __restrict__ mu_neg, const float* __restrict__ kap_neg,
    const float* __restrict__ s_ref, const float* __restrict__ s_pos,
    const float* __restrict__ loss_kappa, float* __restrict__ t_out) {
  __shared__ float muS[128 * 65];   // stride-65: conflict-free scalar reads
  __shared__ float2 rS[4][64];      // [n][d] = (h0, h1)
  __shared__ float posS[8][64];
  __shared__ float rrS[8];          // [h*4+n] = sum_{d>=1} r[d]^2
  __shared__ float wreds[8][2];     // [wave][h] partial exp-sums
  int b = blockIdx.x;
  int t = threadIdx.x;
  int n = t >> 7;                   // 0..3
  int j = t & 127;
  int lane = t & 63;
  int wid = t >> 6;                 // 0..7

  // stage mu via float4 global loads, scalar LDS writes into stride-65 rows
  const float4* mublk4 = (const float4*)(mu_neg + (size_t)b * (NNEG * DD));
  for (int i = t; i < NNEG * 16; i += 512) {
    float4 v4 = mublk4[i];
    float* dst = &muS[(i >> 4) * 65 + ((i & 15) << 2)];
    dst[0] = v4.x; dst[1] = v4.y; dst[2] = v4.z; dst[3] = v4.w;
  }
  {
    int h = wid >> 2, nn = wid & 3;
    size_t row = (size_t)(nn * 4096 + b) + (size_t)h * 16384;
    float rv = s_ref[row * DD + lane];
    if (h == 0) rS[nn][lane].x = rv; else rS[nn][lane].y = rv;
    posS[wid][lane] = s_pos[row * DD + lane];
    float nrsq = wave_sum(lane > 0 ? rv * rv : 0.0f);
    if (lane == 0) rrS[wid] = nrsq;
  }
  __syncthreads();

  int blk = n * 4096 + b;
  float kap = kap_neg[(size_t)b * NNEG + j];
  uint32_t L = (uint32_t)blk * 128u + (uint32_t)j;
  WPair wp = w_pair_shared(kap, L);

  const float* myMu = &muS[j * 65];
  const float2* rSn = rS[n];
  float mu0 = myMu[0];
  float rm0 = 0.f, rm1 = 0.f;
#pragma unroll 7
  for (int d = 0; d < DD-1; ++d) {
    float m1 = myMu[d+1];
    float2 r01 = rSn[d+1];
    rm0 = fmaf(r01.x, m1, rm0);
    rm1 = fmaf(r01.y, m1, rm1);
  }
  float msq = fmaxf(fmaf(-mu0, mu0, 1.0f), 0.0f);   // unit rows: 1 - mu0^2
  float lk  = loss_kappa[0];
  float e0m = 1.0f - mu0;
  float nu  = fmaxf(__builtin_amdgcn_sqrtf(e0m + e0m), 1e-7f); // sqrt(2-2mu0)
  float inu = __builtin_amdgcn_rcpf(nu);
  float2 rfirst = rSn[0];

  // sims: (rv,mv,ss) exact-in-law; ss = a^2+b^2 + WH-chi2_61
  auto simf = [&](float wv, float rm, float rfv, float rr, uint32_t cnt) {
    float2 ab = bm_pair(hash32(cnt + 15u));
    float x3 = bm_one(hash32(cnt));
    float th = fmaf(0.060358835f, x3, 0.99635702f);   // WH: 61*(th)^3
    float s61 = 61.0f * th * th * th;
    float ss  = fmaf(ab.x, ab.x, fmaf(ab.y, ab.y, s61));
    float nr  = fmaxf(__builtin_amdgcn_sqrtf(rr), 1e-6f);
    float pp  = rm * __builtin_amdgcn_rcpf(nr);
    float qq  = __builtin_amdgcn_sqrtf(fmaxf(msq - pp * pp, 0.0f));
    float rv  = nr * ab.x;
    float mv  = fmaf(pp, ab.x, qq * ab.y);
    float c   = __builtin_amdgcn_sqrtf(fmaxf(1.0f - wv * wv, 1e-7f));
    float f   = c * __builtin_amdgcn_rsqf(ss);
    float dd  = (wv * e0m - f * mv) * inu;
    float rz  = rfv * wv + f * rv;
    float ru  = (rfv * e0m - rm) * inu;
    return lk * (rz - 2.0f * dd * ru);
  };
  float sim0 = simf(wp.lo, rm0, rfirst.x, rrS[n],     L << 4);
  float sim1 = simf(wp.hi, rm1, rfirst.y, rrS[4 + n], (2097152u + L) << 4);

  // ---- no-max lse over j (exp2 args bounded ~ +-70, f32-safe) ----
  float z0 = wave_sum(__builtin_amdgcn_exp2f(sim0 * LOG2E));
  float z1 = wave_sum(__builtin_amdgcn_exp2f(sim1 * LOG2E));
  if (lane == 0) { wreds[wid][0] = z0; wreds[wid][1] = z1; }
  __syncthreads();
  float lse0 = LN2 * __builtin_amdgcn_logf(wreds[n*2][0] + wreds[n*2+1][0]);
  float lse1 = LN2 * __builtin_amdgcn_logf(wreds[n*2][1] + wreds[n*2+1][1]);

  // sp dot + final per-(n,h) write: first wave of each segment
  if (j < 64) {
    float sp0 = wave_sum(rSn[lane].x * posS[n][lane]) * lk;
    float sp1 = wave_sum(rSn[lane].y * posS[4+n][lane]) * lk;
    if (lane == 0) {
      float m0  = fmaxf(sp0, lse0);
      float ld0 = m0 + LN2 * __builtin_amdgcn_logf(
          __builtin_amdgcn_exp2f((sp0 - m0) * LOG2E) +
          __builtin_amdgcn_exp2f((lse0 - m0) * LOG2E));
      t_out[blk] = sp0 - ld0;
      float m1  = fmaxf(sp1, lse1);
      float ld1 = m1 + LN2 * __builtin_amdgcn_logf(
          __builtin_amdgcn_exp2f((sp1 - m1) * LOG2E) +
          __builtin_amdgcn_exp2f((lse1 - m1) * LOG2E));
      t_out[blk + 16384] = sp1 - ld1;
    }
  }
}

// ---------------------------------------------------------------------------
// Kernel 3: log_prob per b = logsumexp_n(t) - log(8); out = -mean_b.
// ---------------------------------------------------------------------------
__global__ __launch_bounds__(256) void final_kernel(
    const float* __restrict__ t_tab, float* __restrict__ out) {
  __shared__ float red[256];
  int t = threadIdx.x;
  float acc = 0.f;
  for (int b = t; b < NB; b += 256) {
    float mx = -INFINITY;
    for (int n = 0; n < NS; ++n) mx = fmaxf(mx, t_tab[n * NB + b]);
    float s = 0.f;
    for (int n = 0; n < NS; ++n)
      s += __builtin_amdgcn_exp2f((t_tab[n * NB + b] - mx) * LOG2E);
    acc += mx + LN2 * __builtin_amdgcn_logf(s) - 2.0794415f; // log(8)
  }
  red[t] = acc; __syncthreads();
  for (int s = 128; s > 0; s >>= 1) {
    if (t < s) red[t] += red[t + s];
    __syncthreads();
  }
  if (t == 0) out[0] = -(red[0] / (float)NB);
}

extern "C" void kernel_launch(void* const* d_in, const int* in_sizes, int n_in,
                              void* d_out, int out_size, void* d_ws, size_t ws_size,
                              hipStream_t stream) {
  const float* mu_ref  = (const float*)d_in[0];
  const float* kap_ref = (const float*)d_in[1];
  const float* mu_pos  = (const float*)d_in[2];
  const float* kap_pos = (const float*)d_in[3];
  const float* mu_neg  = (const float*)d_in[4];
  const float* kap_neg = (const float*)d_in[5];
  const float* lk      = (const float*)d_in[6];
  float* out = (float*)d_out;

  uint8_t* ws = (uint8_t*)d_ws;
  float* s_ref = (float*)ws;                                // 8 MB
  float* s_pos = (float*)(ws + 8388608);                    // 8 MB
  float* t_tab = (float*)(ws + 2 * 8388608);                // 128 KB

  refpos_wave<<<4096, 512, 0, stream>>>(mu_ref, kap_ref, mu_pos, kap_pos,
                                        s_ref, s_pos);
  neg_kernel<<<NB, 512, 0, stream>>>(mu_neg, kap_neg,
                                     s_ref, s_pos, lk, t_tab);
  final_kernel<<<1, 256, 0, stream>>>(t_tab, out);
}

// Round 10
// 95.529 us; speedup vs baseline: 1.0926x; 1.0010x over previous
//
#include <hip/hip_runtime.h>
#include <stdint.h>

// ---------------------------------------------------------------------------
// R9 = R7 structure (512-thread neg blocks, 75% occupancy) + per-thread wins:
//  - shared-candidate w: thread (n,j)'s two h-streams share kappa -> ONE
//    rejection-candidate stream yields both draws (distribution-exact).
//  - Wilson-Hilferty chi^2_61 (cube-of-normal) replaces the MT rejection loop.
//  - no-max logsumexp over j (|sim|<=~48, exp2 args safe in f32).
// s_ref/s_pos remain threefry2x32 bit-exact (wave-parallel kernel).
// ---------------------------------------------------------------------------

#define NB 4096
#define NNEG 128
#define DD 64
#define NS 8
#define NIT 64

#define LOG2E 1.4426950408889634f
#define LN2   0.6931471805599453f

__device__ __forceinline__ void tf2x32(uint32_t k0, uint32_t k1,
                                       uint32_t x0, uint32_t x1,
                                       uint32_t& y0, uint32_t& y1) {
  uint32_t ks2 = k0 ^ k1 ^ 0x1BD11BDAu;
  x0 += k0; x1 += k1;
#define TFR(r) { x0 += x1; x1 = __builtin_rotateleft32(x1, r); x1 ^= x0; }
  TFR(13) TFR(15) TFR(26) TFR(6)
  x0 += k1; x1 += ks2 + 1u;
  TFR(17) TFR(29) TFR(16) TFR(24)
  x0 += ks2; x1 += k0 + 2u;
  TFR(13) TFR(15) TFR(26) TFR(6)
  x0 += k0; x1 += k1 + 3u;
  TFR(17) TFR(29) TFR(16) TFR(24)
  x0 += k1; x1 += ks2 + 4u;
  TFR(13) TFR(15) TFR(26) TFR(6)
  x0 += ks2; x1 += k0 + 5u;
#undef TFR
  y0 = x0; y1 = x1;
}

__device__ __forceinline__ float u01f(uint32_t bits) {
  return __uint_as_float(0x3F800000u | (bits >> 9)) - 1.0f;
}

// sqrt(2) * erfinv(2*u01 - 0.99999994), Giles poly pre-scaled by sqrt(2).
__device__ __forceinline__ float normal_from_bits(uint32_t bits) {
  float f = u01f(bits);
  float x = fmaf(f, 2.0f, -0.99999994f);
  float s = fmaf(-x, x, 1.0f);
  float w2 = __builtin_amdgcn_logf(s);
  float p;
  if (w2 > -7.2134752f) {
    float y = fmaf(w2, -0.69314718f, -2.5f);
    p =              3.9742602e-08f;
    p = fmaf(p, y,   4.8546266e-07f);
    p = fmaf(p, y,  -4.9828227e-06f);
    p = fmaf(p, y,  -6.2105281e-06f);
    p = fmaf(p, y,   3.0912003e-04f);
    p = fmaf(p, y,  -1.7730349e-03f);
    p = fmaf(p, y,  -5.9081340e-03f);
    p = fmaf(p, y,   0.34880266f);
    p = fmaf(p, y,   2.1233135f);
  } else {
    float y = __builtin_amdgcn_sqrtf(-0.69314718f * w2) - 3.0f;
    p =             -2.8314572e-04f;
    p = fmaf(p, y,   1.4276565e-04f);
    p = fmaf(p, y,   1.9082601e-03f);
    p = fmaf(p, y,  -5.1950123e-03f);
    p = fmaf(p, y,   8.1168897e-03f);
    p = fmaf(p, y,  -1.0779792e-02f);
    p = fmaf(p, y,   1.3348578e-02f);
    p = fmaf(p, y,   1.4165811f);
    p = fmaf(p, y,   4.0064333f);
  }
  return p * x;
}

struct WPair { float lo, hi; };

__device__ __forceinline__ float wave_sum(float v) {
  for (int m = 32; m; m >>= 1) v += __shfl_xor(v, m, 64);
  return v;
}

// --- cheap counter-hash RNG ------------------------------------------------
__device__ __forceinline__ uint32_t hash32(uint32_t x) {
  x *= 0x9E3779B9u;
  x ^= x >> 16; x *= 0x21f0aaadu;
  x ^= x >> 15; x *= 0x735a2d97u;
  x ^= x >> 15;
  return x;
}

__device__ __forceinline__ float2 bm_pair(uint32_t bits) {
  float u1 = (float)((bits & 0xffffu) + 1u) * (1.0f / 65536.0f);
  float u2 = (float)(bits >> 16) * (1.0f / 65536.0f);
  float r  = __builtin_amdgcn_sqrtf(-2.0f * LN2 * __builtin_amdgcn_logf(u1));
  return {r * __builtin_amdgcn_cosf(u2), r * __builtin_amdgcn_sinf(u2)};
}
__device__ __forceinline__ float bm_one(uint32_t bits) {
  float u1 = (float)((bits & 0xffffu) + 1u) * (1.0f / 65536.0f);
  float u2 = (float)(bits >> 16) * (1.0f / 65536.0f);
  float r  = __builtin_amdgcn_sqrtf(-2.0f * LN2 * __builtin_amdgcn_logf(u1));
  return r * __builtin_amdgcn_cosf(u2);
}

// Shared-candidate w rejection: one stream supplies both h-draws (same kappa).
__device__ WPair w_pair_shared(float kappa, uint32_t L) {
  float s   = __builtin_amdgcn_sqrtf(fmaf(4.0f * kappa, kappa, 3969.0f));
  float bb  = (s - 2.0f * kappa) * (1.0f / 63.0f);
  float aa  = (63.0f + 2.0f * kappa + s) * 0.25f;
  float ab2 = 2.0f * aa * bb;
  float dc  = 2.0f * ab2 * __builtin_amdgcn_rcpf(1.0f + bb) - 261.01749f;
  const float K = 43.668274f;
  float C   = fmaf(K, __builtin_amdgcn_logf(ab2), dc);
  float om_b = 1.0f - bb, op_b = 1.0f + bb;
  uint32_t base = 0x40000000u + (L << 6);
  float w0 = 1.0f, w1 = 1.0f;
  int k = 0;
  for (int it = 0; it < NIT; ++it) {
    if (__all(k >= 2)) break;
    uint32_t bits = hash32(base + (uint32_t)it);
    float eps = fmaxf((float)(bits & 0xffffu) * (1.0f / 65536.0f), 1e-7f);
    float uu  = (float)((bits >> 16) + 1u) * (1.0f / 65536.0f);
    float den = fmaf(-om_b, eps, 1.0f);
    float id  = __builtin_amdgcn_rcpf(den);
    float ct  = fmaf(-op_b, eps, 1.0f) * id;
    float tv  = ab2 * id;
    float lhs = fmaf(-K, __builtin_amdgcn_logf(den), C) - tv;
    bool acc = (lhs >= LN2 * __builtin_amdgcn_logf(uu)) && (k < 2);
    if (acc) {
      if (k == 0) w0 = ct; else w1 = ct;
      ++k;
    }
  }
  return {w0, w1};
}

// ---------------------------------------------------------------------------
// Kernel 1: s_ref / s_pos, bit-exact, one WAVE per (g, r) row-pair.
// ---------------------------------------------------------------------------
__global__ __launch_bounds__(512) void refpos_wave(
    const float* __restrict__ mu_ref, const float* __restrict__ kap_ref,
    const float* __restrict__ mu_pos, const float* __restrict__ kap_pos,
    float* __restrict__ s_ref, float* __restrict__ s_pos) {
  __shared__ uint4 ktS[2][64];   // per-iteration keys {eps0,eps1,u0,u1}
  __shared__ uint2 kvS[2];       // v-keys per group
  int t = threadIdx.x;

  if (t < 128) {
    int g = t >> 6, it = t & 63;
    uint32_t gk0, gk1;
    if (g == 0) {
      uint32_t A0, B0, A1, B1;
      tf2x32(0u, 42u, 0u, 3u, A0, B0);
      tf2x32(0u, 42u, 1u, 4u, A1, B1);
      gk0 = A0; gk1 = A1;                       // kr
    } else {
      uint32_t A2, B2, A0, B0;
      tf2x32(0u, 42u, 2u, 5u, A2, B2);
      tf2x32(0u, 42u, 0u, 3u, A0, B0);
      gk0 = A2; gk1 = B0;                       // kp
    }
    uint32_t C0, D0, C1, D1;
    tf2x32(gk0, gk1, 0u, 2u, C0, D0);
    tf2x32(gk0, gk1, 1u, 3u, C1, D1);
    uint32_t E0, E1;
    tf2x32(C0, C1, 0u, (uint32_t)it, E0, E1);
    uint32_t F0, G0, F1, G1;
    tf2x32(E0, E1, 0u, 2u, F0, G0);
    tf2x32(E0, E1, 1u, 3u, F1, G1);
    ktS[g][it] = {F0, F1, G0, G1};
    if (it == 0) kvS[g] = {D0, D1};
  }
  __syncthreads();

  int wave_id = blockIdx.x * 8 + (t >> 6);      // 0..32767
  int lane = t & 63;
  int g = wave_id >> 14;                        // 0=ref, 1=pos
  int r = wave_id & 16383;                      // n*4096 + b
  int b = r & 4095;
  const float* mu = (g == 0 ? mu_ref : mu_pos) + (size_t)b * DD;
  float kap = (g == 0 ? kap_ref[b] : kap_pos[b]);

  // ---- w phase: lane i evaluates rejection iteration i for both halves ----
  float s   = __builtin_amdgcn_sqrtf(fmaf(4.0f * kap, kap, 3969.0f));
  float bbv = (s - 2.0f * kap) * (1.0f / 63.0f);
  float aav = (63.0f + 2.0f * kap + s) * 0.25f;
  float ab2 = 2.0f * aav * bbv;
  float dcv = 2.0f * ab2 * __builtin_amdgcn_rcpf(1.0f + bbv) - 261.01749f;
  const float K = 43.668274f;
  float C   = fmaf(K, __builtin_amdgcn_logf(ab2), dcv);
  float om_b = 1.0f - bbv, op_b = 1.0f + bbv;

  uint4 kk = ktS[g][lane];
  uint32_t e0, e1, g0, g1;
  tf2x32(kk.x, kk.y, (uint32_t)r, (uint32_t)r + 16384u, e0, e1);
  tf2x32(kk.z, kk.w, (uint32_t)r, (uint32_t)r + 16384u, g0, g1);
  float ct0, ct1;
  bool acc0, acc1;
  {
    float eps = fminf(fmaxf(u01f(e0), 1e-7f), 0.99999988f);
    float den = fmaf(-om_b, eps, 1.0f);
    float id  = __builtin_amdgcn_rcpf(den);
    ct0 = fmaf(-op_b, eps, 1.0f) * id;
    float tv  = ab2 * id;
    float lhs = fmaf(-K, __builtin_amdgcn_logf(den), C) - tv;
    acc0 = lhs >= LN2 * __builtin_amdgcn_logf(u01f(g0));
  }
  {
    float eps = fminf(fmaxf(u01f(e1), 1e-7f), 0.99999988f);
    float den = fmaf(-om_b, eps, 1.0f);
    float id  = __builtin_amdgcn_rcpf(den);
    ct1 = fmaf(-op_b, eps, 1.0f) * id;
    float tv  = ab2 * id;
    float lhs = fmaf(-K, __builtin_amdgcn_logf(den), C) - tv;
    acc1 = lhs >= LN2 * __builtin_amdgcn_logf(u01f(g1));
  }
  unsigned long long m0 = __ballot(acc0);
  unsigned long long m1 = __ballot(acc1);
  int f0i = __ffsll((long long)m0);
  int f1i = __ffsll((long long)m1);
  float w0 = f0i ? __shfl(ct0, f0i - 1, 64) : 1.0f;
  float w1 = f1i ? __shfl(ct1, f1i - 1, 64) : 1.0f;

  // ---- v phase: lane d handles dimension d ----
  uint2 kv = kvS[g];
  float v0 = 0.f, v1 = 0.f, m1v = 0.f;
  if (lane < 63) {
    uint32_t Lv = (uint32_t)r * 63u + (uint32_t)lane;
    uint32_t y0, y1;
    tf2x32(kv.x, kv.y, Lv, Lv + 1032192u, y0, y1);
    v0 = normal_from_bits(y0);
    v1 = normal_from_bits(y1);
    m1v = mu[lane + 1];
  }
  float mu0 = mu[0];
  float ss0 = wave_sum(v0 * v0);
  float ss1 = wave_sum(v1 * v1);
  float mv0 = wave_sum(m1v * v0);
  float mv1 = wave_sum(m1v * v1);
  float msq = wave_sum(m1v * m1v);

  float c0 = __builtin_amdgcn_sqrtf(fmaxf(1.0f - w0 * w0, 1e-7f));
  float c1 = __builtin_amdgcn_sqrtf(fmaxf(1.0f - w1 * w1, 1e-7f));
  float e0m = 1.0f - mu0;
  float nu  = fmaxf(__builtin_amdgcn_sqrtf(e0m * e0m + msq), 1e-7f);
  float inu = __builtin_amdgcn_rcpf(nu);
  float f0 = c0 * __builtin_amdgcn_rsqf(ss0);
  float f1 = c1 * __builtin_amdgcn_rsqf(ss1);
  float dot0 = (w0 * e0m - f0 * mv0) * inu;
  float dot1 = (w1 * e0m - f1 * mv1) * inu;

  float* outp = (g == 0 ? s_ref : s_pos);
  float* row0 = outp + (size_t)r * DD;
  float* row1 = outp + (size_t)(r + 16384) * DD;
  if (lane < 63) {
    float uh = -m1v * inu;
    row0[lane + 1] = f0 * v0 - 2.0f * dot0 * uh;
    row1[lane + 1] = f1 * v1 - 2.0f * dot1 * uh;
  } else {
    row0[0] = w0 - 2.0f * dot0 * (e0m * inu);
    row1[0] = w1 - 2.0f * dot1 * (e0m * inu);
  }
}

// ---------------------------------------------------------------------------
// Kernel 2: negatives. Block = b (512 threads = 4 n-groups x 128 j), R7 shape.
// Shared-candidate w, WH chi^2_61, no-max lse.
// ---------------------------------------------------------------------------
__global__ __launch_bounds__(512, 4) void neg_kernel(
    const float* __restrict__ mu_neg, const float* __restrict__ kap_neg,
    const float* __restrict__ s_ref, const float* __restrict__ s_pos,
    const float* __restrict__ loss_kappa, float* __restrict__ t_out) {
  __shared__ float muS[128 * 65];   // stride-65: conflict-free scalar reads
  __shared__ float2 rS[4][64];      // [n][d] = (h0, h1)
  __shared__ float posS[8][64];
  __shared__ float rrS[8];          // [h*4+n] = sum_{d>=1} r[d]^2
  __shared__ float wreds[8][2];     // [wave][h] partial exp-sums
  int b = blockIdx.x;
  int t = threadIdx.x;
  int n = t >> 7;                   // 0..3
  int j = t & 127;
  int lane = t & 63;
  int wid = t >> 6;                 // 0..7

  // stage mu via float4 global loads, scalar LDS writes into stride-65 rows
  const float4* mublk4 = (const float4*)(mu_neg + (size_t)b * (NNEG * DD));
  for (int i = t; i < NNEG * 16; i += 512) {
    float4 v4 = mublk4[i];
    float* dst = &muS[(i >> 4) * 65 + ((i & 15) << 2)];
    dst[0] = v4.x; dst[1] = v4.y; dst[2] = v4.z; dst[3] = v4.w;
  }
  {
    int h = wid >> 2, nn = wid & 3;
    size_t row = (size_t)(nn * 4096 + b) + (size_t)h * 16384;
    float rv = s_ref[row * DD + lane];
    if (h == 0) rS[nn][lane].x = rv; else rS[nn][lane].y = rv;
    posS[wid][lane] = s_pos[row * DD + lane];
    float nrsq = wave_sum(lane > 0 ? rv * rv : 0.0f);
    if (lane == 0) rrS[wid] = nrsq;
  }
  __syncthreads();

  int blk = n * 4096 + b;
  float kap = kap_neg[(size_t)b * NNEG + j];
  uint32_t L = (uint32_t)blk * 128u + (uint32_t)j;
  WPair wp = w_pair_shared(kap, L);

  const float* myMu = &muS[j * 65];
  const float2* rSn = rS[n];
  float mu0 = myMu[0];
  float rm0 = 0.f, rm1 = 0.f;
#pragma unroll 7
  for (int d = 0; d < DD-1; ++d) {
    float m1 = myMu[d+1];
    float2 r01 = rSn[d+1];
    rm0 = fmaf(r01.x, m1, rm0);
    rm1 = fmaf(r01.y, m1, rm1);
  }
  float msq = fmaxf(fmaf(-mu0, mu0, 1.0f), 0.0f);   // unit rows: 1 - mu0^2
  float lk  = loss_kappa[0];
  float e0m = 1.0f - mu0;
  float nu  = fmaxf(__builtin_amdgcn_sqrtf(e0m + e0m), 1e-7f); // sqrt(2-2mu0)
  float inu = __builtin_amdgcn_rcpf(nu);
  float2 rfirst = rSn[0];

  // sims: (rv,mv,ss) exact-in-law; ss = a^2+b^2 + WH-chi2_61
  auto simf = [&](float wv, float rm, float rfv, float rr, uint32_t cnt) {
    float2 ab = bm_pair(hash32(cnt + 15u));
    float x3 = bm_one(hash32(cnt));
    float th = fmaf(0.060358835f, x3, 0.99635702f);   // WH: 61*(th)^3
    float s61 = 61.0f * th * th * th;
    float ss  = fmaf(ab.x, ab.x, fmaf(ab.y, ab.y, s61));
    float nr  = fmaxf(__builtin_amdgcn_sqrtf(rr), 1e-6f);
    float pp  = rm * __builtin_amdgcn_rcpf(nr);
    float qq  = __builtin_amdgcn_sqrtf(fmaxf(msq - pp * pp, 0.0f));
    float rv  = nr * ab.x;
    float mv  = fmaf(pp, ab.x, qq * ab.y);
    float c   = __builtin_amdgcn_sqrtf(fmaxf(1.0f - wv * wv, 1e-7f));
    float f   = c * __builtin_amdgcn_rsqf(ss);
    float dd  = (wv * e0m - f * mv) * inu;
    float rz  = rfv * wv + f * rv;
    float ru  = (rfv * e0m - rm) * inu;
    return lk * (rz - 2.0f * dd * ru);
  };
  float sim0 = simf(wp.lo, rm0, rfirst.x, rrS[n],     L << 4);
  float sim1 = simf(wp.hi, rm1, rfirst.y, rrS[4 + n], (2097152u + L) << 4);

  // ---- no-max lse over j (exp2 args bounded ~ +-70, f32-safe) ----
  float z0 = wave_sum(__builtin_amdgcn_exp2f(sim0 * LOG2E));
  float z1 = wave_sum(__builtin_amdgcn_exp2f(sim1 * LOG2E));
  if (lane == 0) { wreds[wid][0] = z0; wreds[wid][1] = z1; }
  __syncthreads();
  float lse0 = LN2 * __builtin_amdgcn_logf(wreds[n*2][0] + wreds[n*2+1][0]);
  float lse1 = LN2 * __builtin_amdgcn_logf(wreds[n*2][1] + wreds[n*2+1][1]);

  // sp dot + final per-(n,h) write: first wave of each segment
  if (j < 64) {
    float sp0 = wave_sum(rSn[lane].x * posS[n][lane]) * lk;
    float sp1 = wave_sum(rSn[lane].y * posS[4+n][lane]) * lk;
    if (lane == 0) {
      float m0  = fmaxf(sp0, lse0);
      float ld0 = m0 + LN2 * __builtin_amdgcn_logf(
          __builtin_amdgcn_exp2f((sp0 - m0) * LOG2E) +
          __builtin_amdgcn_exp2f((lse0 - m0) * LOG2E));
      t_out[blk] = sp0 - ld0;
      float m1  = fmaxf(sp1, lse1);
      float ld1 = m1 + LN2 * __builtin_amdgcn_logf(
          __builtin_amdgcn_exp2f((sp1 - m1) * LOG2E) +
          __builtin_amdgcn_exp2f((lse1 - m1) * LOG2E));
      t_out[blk + 16384] = sp1 - ld1;
    }
  }
}

// ---------------------------------------------------------------------------
// Kernel 3: log_prob per b = logsumexp_n(t) - log(8); out = -mean_b.
// ---------------------------------------------------------------------------
__global__ __launch_bounds__(256) void final_kernel(
    const float* __restrict__ t_tab, float* __restrict__ out) {
  __shared__ float red[256];
  int t = threadIdx.x;
  float acc = 0.f;
  for (int b = t; b < NB; b += 256) {
    float mx = -INFINITY;
    for (int n = 0; n < NS; ++n) mx = fmaxf(mx, t_tab[n * NB + b]);
    float s = 0.f;
    for (int n = 0; n < NS; ++n)
      s += __builtin_amdgcn_exp2f((t_tab[n * NB + b] - mx) * LOG2E);
    acc += mx + LN2 * __builtin_amdgcn_logf(s) - 2.0794415f; // log(8)
  }
  red[t] = acc; __syncthreads();
  for (int s = 128; s > 0; s >>= 1) {
    if (t < s) red[t] += red[t + s];
    __syncthreads();
  }
  if (t == 0) out[0] = -(red[0] / (float)NB);
}

extern "C" void kernel_launch(void* const* d_in, const int* in_sizes, int n_in,
                              void* d_out, int out_size, void* d_ws, size_t ws_size,
                              hipStream_t stream) {
  const float* mu_ref  = (const float*)d_in[0];
  const float* kap_ref = (const float*)d_in[1];
  const float* mu_pos  = (const float*)d_in[2];
  const float* kap_pos = (const float*)d_in[3];
  const float* mu_neg  = (const float*)d_in[4];
  const float* kap_neg = (const float*)d_in[5];
  const float* lk      = (const float*)d_in[6];
  float* out = (float*)d_out;

  uint8_t* ws = (uint8_t*)d_ws;
  float* s_ref = (float*)ws;                                // 8 MB
  float* s_pos = (float*)(ws + 8388608);                    // 8 MB
  float* t_tab = (float*)(ws + 2 * 8388608);                // 128 KB

  refpos_wave<<<4096, 512, 0, stream>>>(mu_ref, kap_ref, mu_pos, kap_pos,
                                        s_ref, s_pos);
  neg_kernel<<<NB, 512, 0, stream>>>(mu_neg, kap_neg,
                                     s_ref, s_pos, lk, t_tab);
  final_kernel<<<1, 256, 0, stream>>>(t_tab, out);
}